// Round 11
// baseline (80.657 us; speedup 1.0000x reference)
//
#include <hip/hip_runtime.h>
#include <math.h>

namespace {

constexpr int kMaxNT = 1024;
constexpr int kCells0 = 16 * 3 * 80 * 80;        // 307200
constexpr int kCells1 = 16 * 3 * 40 * 40;        // 76800
constexpr int kCells2 = 16 * 3 * 20 * 20;        // 19200
constexpr int kCellsTotal = kCells0 + kCells1 + kCells2;  // 403200

constexpr int kSlotsPerBlock = 16;               // 4 groups x 4 serial slots
constexpr int kObjBlocks = 256;                  // 1 obj block per CU
constexpr int kObjThreads = kObjBlocks * 256;    // 65536
constexpr int kObjIters = (kCellsTotal + kObjThreads - 1) / kObjThreads;  // 7

// workspace: 12 float accumulators + 1 int counter
// acc[0..2]=lbox, [3..5]=lcls, [6..8]=cnt, [9..11]=obj(base+corr)
__device__ __forceinline__ float softplus_neg(float x) {
  return fmaxf(-x, 0.0f) + log1pf(expf(-fabsf(x)));
}

__global__ void arm_kernel(float* __restrict__ acc, int* __restrict__ counter) {
  int t = threadIdx.x;
  if (t < 12) acc[t] = 0.0f;
  if (t == 12) *counter = 0;
}

// Single wide kernel; partials flow ONLY through device-scope atomics
// (coherent across XCDs without fences -- R9's threadfence was the cost).
// Last-arriving block (completion counter) re-reads the accumulators via
// atomicAdd(p, 0.0f) (coherent read) and writes the 5 outputs.
__global__ __launch_bounds__(256) void main_kernel(
    const float* __restrict__ p0, const float* __restrict__ p1,
    const float* __restrict__ p2, const float* __restrict__ targets,
    const float* __restrict__ anchors,
    float* __restrict__ acc, int* __restrict__ counter,
    float* __restrict__ out, int nt, int bpl) {
  int bid = blockIdx.x;
  int tid = threadIdx.x;
  int group = tid >> 6;
  int lane = tid & 63;

  __shared__ float s0[4], s1[4], s2[4], s3[4];

  if (bid < kObjBlocks) {
    // ---- obj base: 7 independent nontemporal strided ch-4 loads ----
    int flat0 = bid * 256 + tid;
    float x[kObjIters];
#pragma unroll
    for (int j = 0; j < kObjIters; ++j) {
      int cell = flat0 + j * kObjThreads;
      float v = 0.0f;
      if (cell < kCellsTotal) {
        const float* p;
        int rel;
        if (cell < kCells0) { p = p0; rel = cell; }
        else if (cell < kCells0 + kCells1) { p = p1; rel = cell - kCells0; }
        else { p = p2; rel = cell - kCells0 - kCells1; }
        v = __builtin_nontemporal_load(&p[(size_t)rel * 85 + 4]);
      }
      x[j] = v;
    }
    float a0 = 0.f, a1 = 0.f, a2 = 0.f;
#pragma unroll
    for (int j = 0; j < kObjIters; ++j) {
      int cell = flat0 + j * kObjThreads;
      if (cell < kCellsTotal) {
        float v = x[j] + softplus_neg(x[j]);
        if (cell < kCells0) a0 += v;
        else if (cell < kCells0 + kCells1) a1 += v;
        else a2 += v;
      }
    }
    for (int o = 32; o > 0; o >>= 1) {
      a0 += __shfl_xor(a0, o);
      a1 += __shfl_xor(a1, o);
      a2 += __shfl_xor(a2, o);
    }
    if (lane == 0) { s0[group] = a0; s1[group] = a1; s2[group] = a2; }
    __syncthreads();
    if (tid == 0) {
      float t0 = s0[0] + s0[1] + s0[2] + s0[3];
      float t1 = s1[0] + s1[1] + s1[2] + s1[3];
      float t2 = s2[0] + s2[1] + s2[2] + s2[3];
      atomicAdd(&acc[9], t0);
      atomicAdd(&acc[10], t1);
      atomicAdd(&acc[11], t2);
    }
  } else {
    // ---- entry part: 16 slots per block ----
    int ebid = bid - kObjBlocks;
    int level = ebid / bpl;
    int blk = ebid - level * bpl;
    int nslots = 15 * nt;
    int Wi = (level == 0) ? 80 : (level == 1) ? 40 : 20;
    float W = (float)Wi;
    const float* p = (level == 0) ? p0 : (level == 1) ? p1 : p2;

    float lbox_acc = 0.0f, cnt_acc = 0.0f, cls_acc = 0.0f, oc_acc = 0.0f;

    for (int k = 0; k < 4; ++k) {
      int s = blk * kSlotsPerBlock + group * 4 + k;
      if (s >= nslots) break;
      int r = s % 5;
      int pair = s / 5;
      int a = pair / nt;
      int ti = pair - a * nt;
      const float* tg = targets + ti * 6;
      float gx = tg[2] * W, gy = tg[3] * W;
      float gw = tg[4] * W, gh = tg[5] * W;
      float aw = anchors[(level * 3 + a) * 2 + 0];
      float ah = anchors[(level * 3 + a) * 2 + 1];
      float rw = gw / aw, rh = gh / ah;
      float m = fmaxf(fmaxf(rw, 1.0f / rw), fmaxf(rh, 1.0f / rh));
      bool pass = m < 2.91f;

      bool rowok = true;
      float ox = 0.0f, oy = 0.0f;
      if (r == 1)      { rowok = (fmodf(gx, 1.0f) < 0.5f) && (gx > 1.0f); ox = 0.5f; }
      else if (r == 2) { rowok = (fmodf(gy, 1.0f) < 0.5f) && (gy > 1.0f); oy = 0.5f; }
      else if (r == 3) { float gxi = W - gx;
                         rowok = (fmodf(gxi, 1.0f) < 0.5f) && (gxi > 1.0f); ox = -0.5f; }
      else if (r == 4) { float gyi = W - gy;
                         rowok = (fmodf(gyi, 1.0f) < 0.5f) && (gyi > 1.0f); oy = -0.5f; }

      if (!(pass && rowok)) continue;

      int gi = min(max((int)(gx - ox), 0), Wi - 1);  // trunc==floor, operands>0
      int gj = min(max((int)(gy - oy), 0), Wi - 1);
      int b = (int)tg[0];
      int cls = (int)tg[1];
      int cell = ((b * 3 + a) * Wi + gj) * Wi + gi;
      const float* ps = p + (size_t)cell * 85;
      float tbx = gx - (float)gi, tby = gy - (float)gj;

      float px = 2.0f / (1.0f + expf(-ps[0])) - 0.5f;
      float py = 2.0f / (1.0f + expf(-ps[1])) - 0.5f;
      float sw = 2.0f / (1.0f + expf(-ps[2]));
      float sh = 2.0f / (1.0f + expf(-ps[3]));
      float pw = sw * sw * aw;
      float ph = sh * sh * ah;

      const float EPS = 1e-12f;
      float b1x1 = px - pw * 0.5f, b1x2 = px + pw * 0.5f + EPS;
      float b1y1 = py - ph * 0.5f, b1y2 = py + ph * 0.5f + EPS;
      float b2x1 = tbx - gw * 0.5f, b2x2 = tbx + gw * 0.5f + EPS;
      float b2y1 = tby - gh * 0.5f, b2y2 = tby + gh * 0.5f + EPS;
      float iw = fminf(b1x2, b2x2) - fmaxf(b1x1, b2x1);
      float ih = fminf(b1y2, b2y2) - fmaxf(b1y1, b2y1);
      float inter = fmaxf(iw, 0.0f) * fmaxf(ih, 0.0f);
      float w1 = b1x2 - b1x1, h1 = b1y2 - b1y1;
      float w2 = b2x2 - b2x1, h2 = b2y2 - b2y1;
      float uni = w1 * h1 + w2 * h2 - inter;
      float iou = inter / uni;
      float cwd = fmaxf(b1x2, b2x2) - fminf(b1x1, b2x1);
      float chd = fmaxf(b1y2, b2y2) - fminf(b1y1, b2y1);
      float c2 = cwd * cwd + chd * chd;
      float dx = (b2x1 + b2x2) - (b1x1 + b1x2);
      float dy = (b2y1 + b2y2) - (b1y1 + b1y2);
      float rho2 = dx * dx * 0.25f + dy * dy * 0.25f;
      float dat = atanf(w2 / h2) - atanf(w1 / h1);
      float v = 0.4052847345693511f * dat * dat;  // 4/pi^2
      float alpha = v / (1.0f + EPS - iou + v);
      float ciou = iou - (rho2 / c2 + v * alpha);

      // class BCE: lane -> channel lane; lanes 0..15 also channel lane+64
      {
        float x = ps[5 + lane];
        float sp = softplus_neg(x);
        cls_acc += (lane == cls) ? (0.631f * sp) : (x + sp);
      }
      if (lane < 16) {
        int c = lane + 64;
        float x = ps[5 + c];
        float sp = softplus_neg(x);
        cls_acc += (c == cls) ? (0.631f * sp) : (x + sp);
      }

      // obj correction (t = clip(ciou,0)): BCE(x,t)-BCE(x,0)
      float t = fmaxf(ciou, 0.0f);
      float xo = ps[4];
      oc_acc += t * (-xo - 0.089f * softplus_neg(xo));

      lbox_acc += 1.0f - ciou;
      cnt_acc += 1.0f;
    }

    for (int o = 32; o > 0; o >>= 1) cls_acc += __shfl_xor(cls_acc, o);

    if (lane == 0) {
      s0[group] = lbox_acc; s1[group] = cls_acc;
      s2[group] = cnt_acc;  s3[group] = oc_acc;
    }
    __syncthreads();
    if (tid == 0) {
      float tb = s0[0] + s0[1] + s0[2] + s0[3];
      float tc = s1[0] + s1[1] + s1[2] + s1[3];
      float tn = s2[0] + s2[1] + s2[2] + s2[3];
      float to = s3[0] + s3[1] + s3[2] + s3[3];
      if (tn != 0.0f) {  // blocks with no valid slots contribute nothing
        atomicAdd(&acc[0 + level], tb);
        atomicAdd(&acc[3 + level], tc);
        atomicAdd(&acc[6 + level], tn);
        atomicAdd(&acc[9 + level], to);
      }
    }
  }

  // ---- completion: atomics-only handoff (no fences) ----
  __shared__ bool isLast;
  __shared__ float fin[12];
  if (tid == 0) {
    asm volatile("s_waitcnt vmcnt(0)" ::: "memory");  // data atomics complete
    int old = atomicAdd(counter, 1);
    isLast = (old == (int)gridDim.x - 1);
  }
  __syncthreads();
  if (!isLast) return;

  if (tid < 12) fin[tid] = atomicAdd(&acc[tid], 0.0f);  // coherent read
  __syncthreads();
  if (tid == 0) {
    const double bal[3] = {4.0, 1.0, 0.4};
    const double ncl[3] = {(double)kCells0, (double)kCells1, (double)kCells2};
    double lbox = 0.0, lcls = 0.0, lobj = 0.0;
#pragma unroll
    for (int l = 0; l < 3; ++l) {
      double n = (double)fin[6 + l];
      if (n > 0.0) {
        lbox += (double)fin[0 + l] / n;
        lcls += (double)fin[3 + l] / (n * 80.0);
      }
      lobj += (double)fin[9 + l] / ncl[l] * bal[l];
    }
    lbox *= 0.0296;
    lobj *= 0.301;
    lcls *= 0.243;
    double loss = lbox + lobj + lcls;
    out[0] = (float)(loss * 16.0);
    out[1] = (float)lbox;
    out[2] = (float)lobj;
    out[3] = (float)lcls;
    out[4] = (float)loss;
  }
}

}  // namespace

extern "C" void kernel_launch(void* const* d_in, const int* in_sizes, int n_in,
                              void* d_out, int out_size, void* d_ws, size_t ws_size,
                              hipStream_t stream) {
  const float* p0 = (const float*)d_in[0];
  const float* p1 = (const float*)d_in[1];
  const float* p2 = (const float*)d_in[2];
  const float* targets = (const float*)d_in[3];
  const float* anchors = (const float*)d_in[4];
  int nt = in_sizes[3] / 6;
  if (nt > kMaxNT) nt = kMaxNT;
  int nslots = 15 * nt;
  int bpl = (nslots + kSlotsPerBlock - 1) / kSlotsPerBlock;

  float* acc = (float*)d_ws;
  int* counter = (int*)((float*)d_ws + 12);

  arm_kernel<<<1, 64, 0, stream>>>(acc, counter);
  int gridA = kObjBlocks + 3 * bpl;
  main_kernel<<<gridA, 256, 0, stream>>>(p0, p1, p2, targets, anchors,
                                         acc, counter, (float*)d_out, nt, bpl);
}

// Round 12
// 31.552 us; speedup vs baseline: 2.5563x; 2.5563x over previous
//
#include <hip/hip_runtime.h>
#include <math.h>

namespace {

constexpr int kMaxNT = 1024;
constexpr int kCells0 = 16 * 3 * 80 * 80;        // 307200
constexpr int kCells1 = 16 * 3 * 40 * 40;        // 76800
constexpr int kCells2 = 16 * 3 * 20 * 20;        // 19200
constexpr int kCellsTotal = kCells0 + kCells1 + kCells2;  // 403200

constexpr int kSlotsPerBlock = 16;               // 4 groups x 4 serial slots
constexpr int kObjBlocks = 256;                  // exactly 1 obj block per CU
constexpr int kObjThreads = kObjBlocks * 256;    // 65536
constexpr int kObjIters = (kCellsTotal + kObjThreads - 1) / kObjThreads;  // 7

constexpr int kBPLMax = (15 * kMaxNT + kSlotsPerBlock - 1) / kSlotsPerBlock;  // 960

// workspace layout in 4-byte units (write-before-read everywhere; no zeroing)
constexpr size_t kEbOff    = 0;                   // 4 arrays x 3*kBPLMax floats
constexpr size_t kOpartOff = kEbOff + 4 * (3 * kBPLMax);  // 3*kObjBlocks floats

__device__ __forceinline__ float softplus_neg(float x) {
  return fmaxf(-x, 0.0f) + log1pf(expf(-fabsf(x)));
}

// K_A: blocks [0, 256) = obj base sum, balanced 1 block/CU, 7 independent
// nontemporal loads per thread (MLP), contiguous region per block per step.
// Blocks [256, +3*bpl) = fused build + entry losses. No atomics, no fences,
// no in-kernel completion protocol (R7 coop, R9 fence+counter, R11
// atomics-only ALL regressed 2-4x: end-of-block global sync serializes
// cross-XCD and throttles the memory pipe). Two launches is the floor.
// lobj = sum_all BCE(x,0) + sum_entries t*(-x - 0.089*softplus(-x)).
// No-collision validated (absmax 0.0, R3-R11).
__global__ __launch_bounds__(256) void main_kernel(
    const float* __restrict__ p0, const float* __restrict__ p1,
    const float* __restrict__ p2, const float* __restrict__ targets,
    const float* __restrict__ anchors,
    float* __restrict__ eb_lbox, float* __restrict__ eb_lcls,
    float* __restrict__ eb_cnt, float* __restrict__ eb_ocorr,
    float* __restrict__ opart, int nt, int bpl) {
  int bid = blockIdx.x;
  int tid = threadIdx.x;
  int group = tid >> 6;
  int lane = tid & 63;

  if (bid < kObjBlocks) {
    // ---- obj base: gather 7 strided ch-4 values, then compute ----
    int flat0 = bid * 256 + tid;
    float x[kObjIters];
#pragma unroll
    for (int j = 0; j < kObjIters; ++j) {
      int cell = flat0 + j * kObjThreads;
      float v = 0.0f;
      if (cell < kCellsTotal) {
        const float* p;
        int rel;
        if (cell < kCells0) { p = p0; rel = cell; }
        else if (cell < kCells0 + kCells1) { p = p1; rel = cell - kCells0; }
        else { p = p2; rel = cell - kCells0 - kCells1; }
        v = __builtin_nontemporal_load(&p[(size_t)rel * 85 + 4]);
      }
      x[j] = v;
    }
    float a0 = 0.f, a1 = 0.f, a2 = 0.f;
#pragma unroll
    for (int j = 0; j < kObjIters; ++j) {
      int cell = flat0 + j * kObjThreads;
      if (cell < kCellsTotal) {
        float v = x[j] + softplus_neg(x[j]);
        if (cell < kCells0) a0 += v;
        else if (cell < kCells0 + kCells1) a1 += v;
        else a2 += v;
      }
    }
    for (int o = 32; o > 0; o >>= 1) {
      a0 += __shfl_xor(a0, o);
      a1 += __shfl_xor(a1, o);
      a2 += __shfl_xor(a2, o);
    }
    __shared__ float s0[4], s1[4], s2[4];
    if (lane == 0) { s0[group] = a0; s1[group] = a1; s2[group] = a2; }
    __syncthreads();
    if (tid == 0) {
      opart[bid * 3 + 0] = s0[0] + s0[1] + s0[2] + s0[3];
      opart[bid * 3 + 1] = s1[0] + s1[1] + s1[2] + s1[3];
      opart[bid * 3 + 2] = s2[0] + s2[1] + s2[2] + s2[3];
    }
    return;
  }

  // ---- entry part: 16 slots per block ----
  int ebid = bid - kObjBlocks;
  int level = ebid / bpl;
  int blk = ebid - level * bpl;
  int nslots = 15 * nt;
  int Wi = (level == 0) ? 80 : (level == 1) ? 40 : 20;
  float W = (float)Wi;
  const float* p = (level == 0) ? p0 : (level == 1) ? p1 : p2;

  float lbox_acc = 0.0f, cnt_acc = 0.0f, cls_acc = 0.0f, oc_acc = 0.0f;

  for (int k = 0; k < 4; ++k) {
    int s = blk * kSlotsPerBlock + group * 4 + k;
    if (s >= nslots) break;
    int r = s % 5;
    int pair = s / 5;
    int a = pair / nt;
    int ti = pair - a * nt;
    const float* tg = targets + ti * 6;
    float gx = tg[2] * W, gy = tg[3] * W;
    float gw = tg[4] * W, gh = tg[5] * W;
    float aw = anchors[(level * 3 + a) * 2 + 0];
    float ah = anchors[(level * 3 + a) * 2 + 1];
    float rw = gw / aw, rh = gh / ah;
    float m = fmaxf(fmaxf(rw, 1.0f / rw), fmaxf(rh, 1.0f / rh));
    bool pass = m < 2.91f;

    bool rowok = true;
    float ox = 0.0f, oy = 0.0f;
    if (r == 1)      { rowok = (fmodf(gx, 1.0f) < 0.5f) && (gx > 1.0f); ox = 0.5f; }
    else if (r == 2) { rowok = (fmodf(gy, 1.0f) < 0.5f) && (gy > 1.0f); oy = 0.5f; }
    else if (r == 3) { float gxi = W - gx;
                       rowok = (fmodf(gxi, 1.0f) < 0.5f) && (gxi > 1.0f); ox = -0.5f; }
    else if (r == 4) { float gyi = W - gy;
                       rowok = (fmodf(gyi, 1.0f) < 0.5f) && (gyi > 1.0f); oy = -0.5f; }

    if (!(pass && rowok)) continue;

    int gi = min(max((int)(gx - ox), 0), Wi - 1);  // trunc==floor, operands>0
    int gj = min(max((int)(gy - oy), 0), Wi - 1);
    int b = (int)tg[0];
    int cls = (int)tg[1];
    int cell = ((b * 3 + a) * Wi + gj) * Wi + gi;
    const float* ps = p + (size_t)cell * 85;
    float tbx = gx - (float)gi, tby = gy - (float)gj;

    float px = 2.0f / (1.0f + expf(-ps[0])) - 0.5f;
    float py = 2.0f / (1.0f + expf(-ps[1])) - 0.5f;
    float sw = 2.0f / (1.0f + expf(-ps[2]));
    float sh = 2.0f / (1.0f + expf(-ps[3]));
    float pw = sw * sw * aw;
    float ph = sh * sh * ah;

    const float EPS = 1e-12f;
    float b1x1 = px - pw * 0.5f, b1x2 = px + pw * 0.5f + EPS;
    float b1y1 = py - ph * 0.5f, b1y2 = py + ph * 0.5f + EPS;
    float b2x1 = tbx - gw * 0.5f, b2x2 = tbx + gw * 0.5f + EPS;
    float b2y1 = tby - gh * 0.5f, b2y2 = tby + gh * 0.5f + EPS;
    float iw = fminf(b1x2, b2x2) - fmaxf(b1x1, b2x1);
    float ih = fminf(b1y2, b2y2) - fmaxf(b1y1, b2y1);
    float inter = fmaxf(iw, 0.0f) * fmaxf(ih, 0.0f);
    float w1 = b1x2 - b1x1, h1 = b1y2 - b1y1;
    float w2 = b2x2 - b2x1, h2 = b2y2 - b2y1;
    float uni = w1 * h1 + w2 * h2 - inter;
    float iou = inter / uni;
    float cwd = fmaxf(b1x2, b2x2) - fminf(b1x1, b2x1);
    float chd = fmaxf(b1y2, b2y2) - fminf(b1y1, b2y1);
    float c2 = cwd * cwd + chd * chd;
    float dx = (b2x1 + b2x2) - (b1x1 + b1x2);
    float dy = (b2y1 + b2y2) - (b1y1 + b1y2);
    float rho2 = dx * dx * 0.25f + dy * dy * 0.25f;
    float dat = atanf(w2 / h2) - atanf(w1 / h1);
    float v = 0.4052847345693511f * dat * dat;  // 4/pi^2
    float alpha = v / (1.0f + EPS - iou + v);
    float ciou = iou - (rho2 / c2 + v * alpha);

    // class BCE: lane -> channel lane; lanes 0..15 also channel lane+64
    {
      float x = ps[5 + lane];
      float sp = softplus_neg(x);
      cls_acc += (lane == cls) ? (0.631f * sp) : (x + sp);
    }
    if (lane < 16) {
      int c = lane + 64;
      float x = ps[5 + c];
      float sp = softplus_neg(x);
      cls_acc += (c == cls) ? (0.631f * sp) : (x + sp);
    }

    // obj correction for this marked cell (t = clip(ciou, 0))
    float t = fmaxf(ciou, 0.0f);
    float xo = ps[4];
    oc_acc += t * (-xo - 0.089f * softplus_neg(xo));

    lbox_acc += 1.0f - ciou;
    cnt_acc += 1.0f;
  }

  for (int o = 32; o > 0; o >>= 1) cls_acc += __shfl_xor(cls_acc, o);

  __shared__ float sb[4], sc[4], sn[4], so[4];
  if (lane == 0) {
    sb[group] = lbox_acc; sc[group] = cls_acc;
    sn[group] = cnt_acc;  so[group] = oc_acc;
  }
  __syncthreads();
  if (tid == 0) {
    eb_lbox[ebid]  = sb[0] + sb[1] + sb[2] + sb[3];
    eb_lcls[ebid]  = sc[0] + sc[1] + sc[2] + sc[3];
    eb_cnt[ebid]   = sn[0] + sn[1] + sn[2] + sn[3];
    eb_ocorr[ebid] = so[0] + so[1] + so[2] + so[3];
  }
}

// K_B: one block, reduce all partials, write the 5 outputs.
__global__ __launch_bounds__(256) void final_kernel(
    const float* __restrict__ eb_lbox, const float* __restrict__ eb_lcls,
    const float* __restrict__ eb_cnt, const float* __restrict__ eb_ocorr,
    const float* __restrict__ opart, float* __restrict__ out, int bpl) {
  int tid = threadIdx.x;
  int lane = tid & 63, w = tid >> 6;

  double vals[12];  // [0..2] lbox, [3..5] lcls, [6..8] cnt, [9..11] obj
#pragma unroll
  for (int k = 0; k < 12; ++k) vals[k] = 0.0;

#pragma unroll
  for (int lvl = 0; lvl < 3; ++lvl) {
    for (int j = tid; j < bpl; j += 256) {
      int bi = lvl * bpl + j;
      vals[lvl]     += (double)eb_lbox[bi];
      vals[3 + lvl] += (double)eb_lcls[bi];
      vals[6 + lvl] += (double)eb_cnt[bi];
      vals[9 + lvl] += (double)eb_ocorr[bi];
    }
  }
  for (int j = tid; j < kObjBlocks; j += 256) {
    vals[9]  += (double)opart[j * 3 + 0];
    vals[10] += (double)opart[j * 3 + 1];
    vals[11] += (double)opart[j * 3 + 2];
  }

  __shared__ double red[4][12];
#pragma unroll
  for (int k = 0; k < 12; ++k) {
    double v = vals[k];
    for (int o = 32; o > 0; o >>= 1) v += __shfl_xor(v, o);
    if (lane == 0) red[w][k] = v;
  }
  __syncthreads();
  if (tid == 0) {
    const double bal[3] = {4.0, 1.0, 0.4};
    const double ncl[3] = {(double)kCells0, (double)kCells1, (double)kCells2};
    double lbox = 0.0, lcls = 0.0, lobj = 0.0;
#pragma unroll
    for (int l = 0; l < 3; ++l) {
      double sB = red[0][l] + red[1][l] + red[2][l] + red[3][l];
      double sC = red[0][3 + l] + red[1][3 + l] + red[2][3 + l] + red[3][3 + l];
      double n  = red[0][6 + l] + red[1][6 + l] + red[2][6 + l] + red[3][6 + l];
      double sO = red[0][9 + l] + red[1][9 + l] + red[2][9 + l] + red[3][9 + l];
      if (n > 0.0) {
        lbox += sB / n;
        lcls += sC / (n * 80.0);
      }
      lobj += sO / ncl[l] * bal[l];
    }
    lbox *= 0.0296;
    lobj *= 0.301;
    lcls *= 0.243;
    double loss = lbox + lobj + lcls;
    out[0] = (float)(loss * 16.0);
    out[1] = (float)lbox;
    out[2] = (float)lobj;
    out[3] = (float)lcls;
    out[4] = (float)loss;
  }
}

}  // namespace

extern "C" void kernel_launch(void* const* d_in, const int* in_sizes, int n_in,
                              void* d_out, int out_size, void* d_ws, size_t ws_size,
                              hipStream_t stream) {
  const float* p0 = (const float*)d_in[0];
  const float* p1 = (const float*)d_in[1];
  const float* p2 = (const float*)d_in[2];
  const float* targets = (const float*)d_in[3];
  const float* anchors = (const float*)d_in[4];
  int nt = in_sizes[3] / 6;
  if (nt > kMaxNT) nt = kMaxNT;
  int nslots = 15 * nt;
  int bpl = (nslots + kSlotsPerBlock - 1) / kSlotsPerBlock;

  float* wsf = (float*)d_ws;
  float* eb_lbox = wsf + kEbOff;
  float* eb_lcls = eb_lbox + 3 * kBPLMax;
  float* eb_cnt = eb_lcls + 3 * kBPLMax;
  float* eb_ocorr = eb_cnt + 3 * kBPLMax;
  float* opart = wsf + kOpartOff;

  int gridA = kObjBlocks + 3 * bpl;
  main_kernel<<<gridA, 256, 0, stream>>>(p0, p1, p2, targets, anchors,
                                         eb_lbox, eb_lcls, eb_cnt, eb_ocorr,
                                         opart, nt, bpl);
  final_kernel<<<1, 256, 0, stream>>>(eb_lbox, eb_lcls, eb_cnt, eb_ocorr, opart,
                                      (float*)d_out, bpl);
}